// Round 4
// baseline (38.569 us; speedup 1.0000x reference)
//
#include <hip/hip_runtime.h>
#include <hip/hip_bf16.h>

typedef __attribute__((ext_vector_type(8))) short bf16x8;
typedef __attribute__((ext_vector_type(4))) float f32x4;

#define NBH 128   // blocks for hist/scatter
#define TILE 16
#define NBX 64    // blocks-x for k_main (x10 types)

__device__ __forceinline__ unsigned short f2bf(float f) {
    unsigned u = __float_as_uint(f);
    return (unsigned short)((u + 0x7fffu + ((u >> 16) & 1u)) >> 16);
}

__device__ __forceinline__ bf16x8 pack8(float4 x, float4 y) {
    bf16x8 r;
    r[0] = (short)f2bf(x.x); r[1] = (short)f2bf(x.y);
    r[2] = (short)f2bf(x.z); r[3] = (short)f2bf(x.w);
    r[4] = (short)f2bf(y.x); r[5] = (short)f2bf(y.y);
    r[6] = (short)f2bf(y.z); r[7] = (short)f2bf(y.w);
    return r;
}

__device__ __forceinline__ float ftanh(float x) {
    float e = __expf(2.f * x);
    return 1.f - 2.f / (e + 1.f);
}

// ---------------- pass 1: ballot histogram + weight pre-pack ----------------
// blocks [0,NBH): histogram; blocks [NBH,NBH+11): pack layer1 t=0..9, lin_w (NBH+10)
__global__ void k_hist_pack(const int* __restrict__ ij, int* __restrict__ bhist,
                            const float* __restrict__ layer1, const float* __restrict__ lin_w,
                            __hip_bfloat16* __restrict__ wpack, __hip_bfloat16* __restrict__ lpack,
                            int E) {
    if (blockIdx.x < NBH) {
        __shared__ int lh[5][10];
        const int lane = threadIdx.x & 63;
        const int w = threadIdx.x >> 6;
        if (threadIdx.x < 50) ((int*)lh)[threadIdx.x] = 0;
        __syncthreads();
        int cnt[10];
        #pragma unroll
        for (int t = 0; t < 10; ++t) cnt[t] = 0;
        const int nv = E >> 2;
        const int4* ij4 = (const int4*)ij;
        for (int i = blockIdx.x * 256 + threadIdx.x; i < nv; i += NBH * 256) {
            const int4 v = ij4[i];
            #pragma unroll
            for (int j = 0; j < 4; ++j) {
                const int ty = (j == 0) ? v.x : (j == 1) ? v.y : (j == 2) ? v.z : v.w;
                #pragma unroll
                for (int t = 0; t < 10; ++t)
                    cnt[t] += (int)__popcll(__ballot(ty == t));
            }
        }
        if (lane == 0) {
            #pragma unroll
            for (int t = 0; t < 10; ++t) lh[w][t] = cnt[t];
        }
        // tail edges -> attributed to block 0
        if (blockIdx.x == 0) {
            for (int e = (E & ~3) + threadIdx.x; e < E; e += 256)
                atomicAdd(&lh[4][ij[e]], 1);
        }
        __syncthreads();
        if (threadIdx.x < 10) {
            const int t = threadIdx.x;
            bhist[blockIdx.x * 10 + t] = lh[0][t] + lh[1][t] + lh[2][t] + lh[3][t] + lh[4][t];
        }
    } else {
        const int t = blockIdx.x - NBH;
        const float* src = (t < 10) ? (layer1 + t * 4096) : lin_w;
        __hip_bfloat16* dst = (t < 10) ? (wpack + t * 4096) : lpack;
        for (int idx = threadIdx.x; idx < 512; idx += 256) {
            const int fi = idx >> 6, l = idx & 63;
            const int nt = fi >> 1, kk = fi & 1;
            const float* sp = src + (nt * 16 + (l & 15)) * 64 + kk * 32 + (l >> 4) * 8;
            float4 x = *(const float4*)sp;
            float4 y = *(const float4*)(sp + 4);
            *(bf16x8*)(dst + fi * 512 + l * 8) = pack8(x, y);
        }
    }
}

// ---------------- pass 2: fused prefix + wave-aggregated scatter ----------------
__global__ void k_scatter2(const int* __restrict__ ij, const int* __restrict__ bhist,
                           int* __restrict__ perm, int* __restrict__ cnt, int* __restrict__ poff,
                           int E) {
    __shared__ int lh[NBH * 10];
    __shared__ int ctot[10];
    __shared__ int lpof[10];
    __shared__ int wc[10];
    for (int i = threadIdx.x; i < NBH * 10; i += 256) lh[i] = bhist[i];
    __syncthreads();
    int mypre = 0;
    if (threadIdx.x < 10) {
        const int t = threadIdx.x;
        int pre = 0, tot = 0;
        for (int b = 0; b < NBH; ++b) {
            if (b == (int)blockIdx.x) pre = tot;
            tot += lh[b * 10 + t];
        }
        ctot[t] = tot;
        mypre = pre;
    }
    __syncthreads();
    if (threadIdx.x == 0) {
        int acc = 0;
        for (int t = 0; t < 10; ++t) { lpof[t] = acc; acc += ((ctot[t] + TILE - 1) / TILE) * TILE; }
    }
    __syncthreads();
    if (threadIdx.x < 10) {
        wc[threadIdx.x] = lpof[threadIdx.x] + mypre;
        if (blockIdx.x == 0) { cnt[threadIdx.x] = ctot[threadIdx.x]; poff[threadIdx.x] = lpof[threadIdx.x]; }
    }
    __syncthreads();
    const int lane = threadIdx.x & 63;
    const unsigned long long ltm = (1ull << lane) - 1ull;
    const int nv = E >> 2;
    const int4* ij4 = (const int4*)ij;
    for (int i = blockIdx.x * 256 + threadIdx.x; i < nv; i += NBH * 256) {
        const int4 v = ij4[i];
        #pragma unroll
        for (int j = 0; j < 4; ++j) {
            const int ty = (j == 0) ? v.x : (j == 1) ? v.y : (j == 2) ? v.z : v.w;
            const int e = i * 4 + j;
            #pragma unroll
            for (int t = 0; t < 10; ++t) {
                const unsigned long long m = __ballot(ty == t);
                if (m) {
                    const int c = (int)__popcll(m);
                    const int leader = __ffsll((long long)m) - 1;
                    int base = 0;
                    if (lane == leader) base = atomicAdd(&wc[t], c);
                    base = __shfl(base, leader);
                    if (ty == t) perm[base + (int)__popcll(m & ltm)] = e;
                }
            }
        }
    }
    if (blockIdx.x == 0) {
        for (int e = (E & ~3) + threadIdx.x; e < E; e += 256) {
            const int t = ij[e];
            const int r = atomicAdd(&wc[t], 1);
            perm[r] = e;
        }
    }
}

// ---------------- pass 3: MFMA main, 2-stage software pipeline ----------------
// A = weights (M=64 outputs), B = desc (N=16 edges), K=64.
// D: col(lane&15)=edge, row((lane>>4)*4+r)=output -> one float4 store per nt.
__global__ __launch_bounds__(256) void k_main(
    const int* __restrict__ perm, const int* __restrict__ cnt, const int* __restrict__ poff,
    const float* __restrict__ desc, const __hip_bfloat16* __restrict__ wpack,
    const __hip_bfloat16* __restrict__ lpack, const float* __restrict__ lin_b,
    float* __restrict__ out) {
    const int t = blockIdx.y;
    const int cn = cnt[t];
    if (cn == 0) return;
    const int ntiles = (cn + TILE - 1) / TILE;
    const int lane = threadIdx.x & 63;
    const int w = threadIdx.x >> 6;
    const int col = lane & 15;
    const int g = lane >> 4;
    const int kb = g * 8;
    const int pbase = poff[t];
    const int step = NBX * 4;

    int tile = blockIdx.x * 4 + w;
    bool act = tile < ntiles;
    int e_cur = 0;
    if (act) e_cur = perm[pbase + min(tile * TILE + col, cn - 1)];   // in flight during setup

    const __hip_bfloat16* wp = wpack + t * 4096;
    bf16x8 aw[4][2], al[4][2];
    #pragma unroll
    for (int fi = 0; fi < 8; ++fi) {
        aw[fi >> 1][fi & 1] = *(const bf16x8*)(wp + fi * 512 + lane * 8);
        al[fi >> 1][fi & 1] = *(const bf16x8*)(lpack + fi * 512 + lane * 8);
    }
    float4 bias[4];
    #pragma unroll
    for (int nt = 0; nt < 4; ++nt) bias[nt] = *(const float4*)(lin_b + nt * 16 + g * 4);

    float4 xc0 = {}, yc0 = {}, xc1 = {}, yc1 = {};
    float4 xn0 = {}, yn0 = {}, xn1 = {}, yn1 = {};
    if (act) {
        const float* dp = desc + (size_t)e_cur * 64 + kb;
        xc0 = *(const float4*)dp; yc0 = *(const float4*)(dp + 4);
        xc1 = *(const float4*)(dp + 32); yc1 = *(const float4*)(dp + 36);
    }
    int tile2 = tile + step;
    bool act2 = tile2 < ntiles;
    int e_nxt = 0;
    if (act2) e_nxt = perm[pbase + min(tile2 * TILE + col, cn - 1)];

    while (act) {
        // issue next tile's desc loads + tile+2's perm load (hidden under compute)
        if (act2) {
            const float* dp = desc + (size_t)e_nxt * 64 + kb;
            xn0 = *(const float4*)dp; yn0 = *(const float4*)(dp + 4);
            xn1 = *(const float4*)(dp + 32); yn1 = *(const float4*)(dp + 36);
        }
        const int tile3 = tile2 + step;
        const bool act3 = tile3 < ntiles;
        int e_n2 = 0;
        if (act3) e_n2 = perm[pbase + min(tile3 * TILE + col, cn - 1)];

        // compute current tile
        const bf16x8 b0 = pack8(xc0, yc0);
        const bf16x8 b1 = pack8(xc1, yc1);
        float* op = out + (size_t)e_cur * 64 + g * 4;
        #pragma unroll
        for (int nt = 0; nt < 4; ++nt) {
            f32x4 z = {0.f, 0.f, 0.f, 0.f}, y2 = {0.f, 0.f, 0.f, 0.f};
            z = __builtin_amdgcn_mfma_f32_16x16x32_bf16(aw[nt][0], b0, z, 0, 0, 0);
            z = __builtin_amdgcn_mfma_f32_16x16x32_bf16(aw[nt][1], b1, z, 0, 0, 0);
            y2 = __builtin_amdgcn_mfma_f32_16x16x32_bf16(al[nt][0], b0, y2, 0, 0, 0);
            y2 = __builtin_amdgcn_mfma_f32_16x16x32_bf16(al[nt][1], b1, y2, 0, 0, 0);
            f32x4 r;
            r[0] = ftanh(z[0]) + y2[0] + bias[nt].x;
            r[1] = ftanh(z[1]) + y2[1] + bias[nt].y;
            r[2] = ftanh(z[2]) + y2[2] + bias[nt].z;
            r[3] = ftanh(z[3]) + y2[3] + bias[nt].w;
            __builtin_nontemporal_store(r, (f32x4*)(op + nt * 16));
        }
        // rotate pipeline
        xc0 = xn0; yc0 = yn0; xc1 = xn1; yc1 = yn1;
        e_cur = e_nxt; act = act2;
        e_nxt = e_n2; tile2 = tile3; act2 = act3;
    }
}

// ---------------- fallback (ws too small): wave-per-edge fp32 ----------------
__global__ void k_naive(const int* __restrict__ ij, const float* __restrict__ desc,
                        const float* __restrict__ layer1, const float* __restrict__ lin_w,
                        const float* __restrict__ lin_b, float* __restrict__ out, int E) {
    const int wid = (blockIdx.x * blockDim.x + threadIdx.x) >> 6;
    const int lane = threadIdx.x & 63;
    const int nw = (gridDim.x * blockDim.x) >> 6;
    for (int e = wid; e < E; e += nw) {
        const int t = ij[e];
        const float d = desc[(size_t)e * 64 + lane];
        const float* Wr = layer1 + t * 4096 + lane * 64;
        const float* Lr = lin_w + lane * 64;
        float a1 = 0.f, a2 = 0.f;
        #pragma unroll
        for (int i = 0; i < 64; i += 4) {
            float4 w4 = *(const float4*)(Wr + i);
            float4 l4 = *(const float4*)(Lr + i);
            const float d0 = __shfl(d, i), d1 = __shfl(d, i + 1);
            const float d2 = __shfl(d, i + 2), d3 = __shfl(d, i + 3);
            a1 = fmaf(w4.x, d0, fmaf(w4.y, d1, fmaf(w4.z, d2, fmaf(w4.w, d3, a1))));
            a2 = fmaf(l4.x, d0, fmaf(l4.y, d1, fmaf(l4.z, d2, fmaf(l4.w, d3, a2))));
        }
        out[(size_t)e * 64 + lane] = tanhf(a1) + a2 + lin_b[lane];
    }
}

extern "C" void kernel_launch(void* const* d_in, const int* in_sizes, int n_in,
                              void* d_out, int out_size, void* d_ws, size_t ws_size,
                              hipStream_t stream) {
    const int* ij = (const int*)d_in[0];
    const float* desc = (const float*)d_in[1];
    const float* layer1 = (const float*)d_in[2];
    const float* lin_w = (const float*)d_in[3];
    const float* lin_b = (const float*)d_in[4];
    float* out = (float*)d_out;
    const int E = in_sizes[0];

    const size_t need = (size_t)(E + 256 + NBH * 10 + 64) * sizeof(int)
                      + (size_t)11 * 4096 * sizeof(__hip_bfloat16) + 64;
    if (ws_size < need) {
        k_naive<<<2048, 256, 0, stream>>>(ij, desc, layer1, lin_w, lin_b, out, E);
        return;
    }
    int* perm = (int*)d_ws;                    // E + 256 ints (padded bins)
    int* bhist = perm + E + 256;               // NBH*10
    int* cnt = bhist + NBH * 10;               // 16 slots
    int* poff = cnt + 16;                      // 16 slots
    __hip_bfloat16* wpack = (__hip_bfloat16*)(poff + 16);  // 10*4096 bf16
    __hip_bfloat16* lpack = wpack + 10 * 4096;             // 4096 bf16

    k_hist_pack<<<NBH + 11, 256, 0, stream>>>(ij, bhist, layer1, lin_w, wpack, lpack, E);
    k_scatter2<<<NBH, 256, 0, stream>>>(ij, bhist, perm, cnt, poff, E);
    k_main<<<dim3(NBX, 10), 256, 0, stream>>>(perm, cnt, poff, desc, wpack, lpack, lin_b, out);
}

// Round 5
// 30.293 us; speedup vs baseline: 1.2732x; 1.2732x over previous
//
#include <hip/hip_runtime.h>
#include <hip/hip_bf16.h>

typedef __attribute__((ext_vector_type(8))) short bf16x8;
typedef __attribute__((ext_vector_type(4))) float f32x4;

#define NBH 128   // blocks for binning
#define TILE 16
#define NBX 128   // blocks-x for k_main (x10 types)

__device__ __forceinline__ unsigned short f2bf(float f) {
    unsigned u = __float_as_uint(f);
    return (unsigned short)((u + 0x7fffu + ((u >> 16) & 1u)) >> 16);
}

__device__ __forceinline__ bf16x8 pack8(float4 x, float4 y) {
    bf16x8 r;
    r[0] = (short)f2bf(x.x); r[1] = (short)f2bf(x.y);
    r[2] = (short)f2bf(x.z); r[3] = (short)f2bf(x.w);
    r[4] = (short)f2bf(y.x); r[5] = (short)f2bf(y.y);
    r[6] = (short)f2bf(y.z); r[7] = (short)f2bf(y.w);
    return r;
}

__device__ __forceinline__ float ftanh(float x) {
    float e = __expf(2.f * x);
    return 1.f - 2.f / (e + 1.f);
}

// ---------------- pass 1: single-pass binning + weight pre-pack ----------------
// blocks [0,NBH): bin edges into perm[t*E + ...] via LDS ranks + one global
// atomicAdd per (block,type). blocks [NBH,NBH+11): pack layer1 t=0..9, lin_w.
// gcnt must be zeroed before launch (memset node).
__global__ void k_bin_pack(const int* __restrict__ ij, int* __restrict__ gcnt,
                           int* __restrict__ perm,
                           const float* __restrict__ layer1, const float* __restrict__ lin_w,
                           __hip_bfloat16* __restrict__ wpack, __hip_bfloat16* __restrict__ lpack,
                           int E) {
    if (blockIdx.x < NBH) {
        __shared__ int lh[10];
        __shared__ int gbase[10];
        if (threadIdx.x < 10) lh[threadIdx.x] = 0;
        __syncthreads();
        const int nv = E >> 2;
        const int4* ij4 = (const int4*)ij;
        const int i = blockIdx.x * 256 + threadIdx.x;   // NBH*256 == 32768 threads; nv <= 32768 for E<=131072
        int4 v = {};
        int rk[4];
        const bool have = i < nv;
        if (have) {
            v = ij4[i];
            rk[0] = atomicAdd(&lh[v.x], 1);
            rk[1] = atomicAdd(&lh[v.y], 1);
            rk[2] = atomicAdd(&lh[v.z], 1);
            rk[3] = atomicAdd(&lh[v.w], 1);
        }
        // tail (E not multiple of 4): at most 3 edges, block 0
        int ttail = -1, rtail = 0, etail = 0;
        if (blockIdx.x == 0 && threadIdx.x < (E & 3)) {
            etail = (nv << 2) + threadIdx.x;
            ttail = ij[etail];
            rtail = atomicAdd(&lh[ttail], 1);
        }
        __syncthreads();
        if (threadIdx.x < 10) gbase[threadIdx.x] = atomicAdd(&gcnt[threadIdx.x], lh[threadIdx.x]);
        __syncthreads();
        if (have) {
            const int e = i << 2;
            perm[v.x * E + gbase[v.x] + rk[0]] = e;
            perm[v.y * E + gbase[v.y] + rk[1]] = e + 1;
            perm[v.z * E + gbase[v.z] + rk[2]] = e + 2;
            perm[v.w * E + gbase[v.w] + rk[3]] = e + 3;
        }
        if (ttail >= 0) perm[ttail * E + gbase[ttail] + rtail] = etail;
    } else {
        const int t = blockIdx.x - NBH;
        const float* src = (t < 10) ? (layer1 + t * 4096) : lin_w;
        __hip_bfloat16* dst = (t < 10) ? (wpack + t * 4096) : lpack;
        for (int idx = threadIdx.x; idx < 512; idx += 256) {
            const int fi = idx >> 6, l = idx & 63;
            const int nt = fi >> 1, kk = fi & 1;
            const float* sp = src + (nt * 16 + (l & 15)) * 64 + kk * 32 + (l >> 4) * 8;
            float4 x = *(const float4*)sp;
            float4 y = *(const float4*)(sp + 4);
            *(bf16x8*)(dst + fi * 512 + l * 8) = pack8(x, y);
        }
    }
}

// ---------------- pass 2: MFMA main (round-2 proven body) ----------------
// A = weights (M=64 outputs), B = desc (N=16 edges), K=64.
// D: col(lane&15)=edge, row((lane>>4)*4+r)=output -> one float4 store per nt.
__global__ __launch_bounds__(256) void k_main(
    const int* __restrict__ perm, const int* __restrict__ gcnt,
    const float* __restrict__ desc, const __hip_bfloat16* __restrict__ wpack,
    const __hip_bfloat16* __restrict__ lpack, const float* __restrict__ lin_b,
    float* __restrict__ out, int E) {
    const int t = blockIdx.y;
    const int cn = gcnt[t];
    if (cn == 0) return;
    const int ntiles = (cn + TILE - 1) / TILE;
    const int lane = threadIdx.x & 63;
    const int w = threadIdx.x >> 6;
    const int gw = blockIdx.x * 4 + w;
    const int col = lane & 15;
    const int g = lane >> 4;
    const int kb = g * 8;
    const int pbase = t * E;
    const __hip_bfloat16* wp = wpack + t * 4096;

    bf16x8 aw[4][2], al[4][2];
    #pragma unroll
    for (int fi = 0; fi < 8; ++fi) {
        aw[fi >> 1][fi & 1] = *(const bf16x8*)(wp + fi * 512 + lane * 8);
        al[fi >> 1][fi & 1] = *(const bf16x8*)(lpack + fi * 512 + lane * 8);
    }
    float4 bias[4];
    #pragma unroll
    for (int nt = 0; nt < 4; ++nt) bias[nt] = *(const float4*)(lin_b + nt * 16 + g * 4);

    for (int tile = gw; tile < ntiles; tile += NBX * 4) {
        const int jb = tile * TILE;
        const int e = perm[pbase + min(jb + col, cn - 1)];
        bf16x8 b[2];
        #pragma unroll
        for (int kk = 0; kk < 2; ++kk) {
            const float* dp = desc + (size_t)e * 64 + kk * 32 + kb;
            float4 x = *(const float4*)dp;
            float4 y = *(const float4*)(dp + 4);
            b[kk] = pack8(x, y);
        }
        #pragma unroll
        for (int nt = 0; nt < 4; ++nt) {
            f32x4 z = {0.f, 0.f, 0.f, 0.f}, y2 = {0.f, 0.f, 0.f, 0.f};
            z = __builtin_amdgcn_mfma_f32_16x16x32_bf16(aw[nt][0], b[0], z, 0, 0, 0);
            z = __builtin_amdgcn_mfma_f32_16x16x32_bf16(aw[nt][1], b[1], z, 0, 0, 0);
            y2 = __builtin_amdgcn_mfma_f32_16x16x32_bf16(al[nt][0], b[0], y2, 0, 0, 0);
            y2 = __builtin_amdgcn_mfma_f32_16x16x32_bf16(al[nt][1], b[1], y2, 0, 0, 0);
            float4 r;
            r.x = ftanh(z[0]) + y2[0] + bias[nt].x;
            r.y = ftanh(z[1]) + y2[1] + bias[nt].y;
            r.z = ftanh(z[2]) + y2[2] + bias[nt].z;
            r.w = ftanh(z[3]) + y2[3] + bias[nt].w;
            *(float4*)(out + (size_t)e * 64 + nt * 16 + g * 4) = r;
        }
    }
}

// ---------------- fallback (ws too small): wave-per-edge fp32 ----------------
__global__ void k_naive(const int* __restrict__ ij, const float* __restrict__ desc,
                        const float* __restrict__ layer1, const float* __restrict__ lin_w,
                        const float* __restrict__ lin_b, float* __restrict__ out, int E) {
    const int wid = (blockIdx.x * blockDim.x + threadIdx.x) >> 6;
    const int lane = threadIdx.x & 63;
    const int nw = (gridDim.x * blockDim.x) >> 6;
    for (int e = wid; e < E; e += nw) {
        const int t = ij[e];
        const float d = desc[(size_t)e * 64 + lane];
        const float* Wr = layer1 + t * 4096 + lane * 64;
        const float* Lr = lin_w + lane * 64;
        float a1 = 0.f, a2 = 0.f;
        #pragma unroll
        for (int i = 0; i < 64; i += 4) {
            float4 w4 = *(const float4*)(Wr + i);
            float4 l4 = *(const float4*)(Lr + i);
            const float d0 = __shfl(d, i), d1 = __shfl(d, i + 1);
            const float d2 = __shfl(d, i + 2), d3 = __shfl(d, i + 3);
            a1 = fmaf(w4.x, d0, fmaf(w4.y, d1, fmaf(w4.z, d2, fmaf(w4.w, d3, a1))));
            a2 = fmaf(l4.x, d0, fmaf(l4.y, d1, fmaf(l4.z, d2, fmaf(l4.w, d3, a2))));
        }
        out[(size_t)e * 64 + lane] = tanhf(a1) + a2 + lin_b[lane];
    }
}

extern "C" void kernel_launch(void* const* d_in, const int* in_sizes, int n_in,
                              void* d_out, int out_size, void* d_ws, size_t ws_size,
                              hipStream_t stream) {
    const int* ij = (const int*)d_in[0];
    const float* desc = (const float*)d_in[1];
    const float* layer1 = (const float*)d_in[2];
    const float* lin_w = (const float*)d_in[3];
    const float* lin_b = (const float*)d_in[4];
    float* out = (float*)d_out;
    const int E = in_sizes[0];

    const size_t need = (size_t)(16 + 10 * (size_t)E) * sizeof(int)
                      + (size_t)11 * 4096 * sizeof(__hip_bfloat16) + 64;
    if (ws_size < need || E > NBH * 256 * 4) {
        k_naive<<<2048, 256, 0, stream>>>(ij, desc, layer1, lin_w, lin_b, out, E);
        return;
    }
    int* gcnt = (int*)d_ws;                               // 16 ints
    int* perm = gcnt + 16;                                // 10*E ints (per-type capacity E)
    __hip_bfloat16* wpack = (__hip_bfloat16*)(perm + 10 * (size_t)E);  // 10*4096 bf16
    __hip_bfloat16* lpack = wpack + 10 * 4096;                          // 4096 bf16

    hipMemsetAsync(gcnt, 0, 16 * sizeof(int), stream);
    k_bin_pack<<<NBH + 11, 256, 0, stream>>>(ij, gcnt, perm, layer1, lin_w, wpack, lpack, E);
    k_main<<<dim3(NBX, 10), 256, 0, stream>>>(perm, gcnt, desc, wpack, lpack, lin_b, out, E);
}